// Round 1
// 564.297 us; speedup vs baseline: 1.2292x; 1.2292x over previous
//
#include <hip/hip_runtime.h>

// Linear_6983616824492: e3nn-style irrep linear, B=50000, blocks (mul,d):
// (256,1)@off0, (256,3)@off256, (128,5)@off1024, row = 1664 fp32.
// v2: LDS-staged A operand. Previous version's per-lane scattered A loads
// (16 B useful per 64 B line, ~4x minimum TA transactions) made the kernel
// request-rate bound (HBM 20%, VALU 10%, MFMA 4%). Now: coalesced float4
// global loads -> bf16 -> XOR-swizzled LDS ([row][col] bf16, row stride
// multiple of 128 B, so swizzle byte^=(row&7)<<4 breaks the 16-way bank
// conflict) -> ds_read_b128 fragments -> in-register stride-D repack.
// B operand (prep-swizzled bf16 in d_ws, L2-resident) and store epilogue
// unchanged from the verified v1.

typedef __attribute__((ext_vector_type(8))) short short8;   // 8 bf16 (4 VGPRs)
typedef __attribute__((ext_vector_type(4))) float f32x4;    // MFMA C/D frag

#define NBATCH 50000
#define NTOTAL 1664

__device__ __forceinline__ unsigned short f2bf(float f) {
    union { float f; unsigned u; } v; v.f = f;
    unsigned r = v.u + 0x7fffu + ((v.u >> 16) & 1u);  // round-nearest-even
    return (unsigned short)(r >> 16);
}

// ---------------- prep: swizzled bf16 B operands into workspace -------------
// Per block, flat element e: j = e&7, lane = (e>>3)&63, qt = e>>9,
// t = qt % NT, q = qt / NT.  value = bf16(W[(q*32 + (lane>>4)*8 + j)*N
//                                          + t*16 + (lane&15)])
// Main kernel loads short8 at index (q*NT + t)*64 + lane (1KB/wave instr,
// L2-resident: 288KB total).
__global__ void prep_kernel(const float* __restrict__ w0,
                            const float* __restrict__ w1,
                            const float* __restrict__ w2,
                            unsigned short* __restrict__ ws) {
    int e = blockIdx.x * blockDim.x + threadIdx.x;
    const float* W; int N, base;
    if (e < 65536)       { W = w0; N = 256; base = 0; }
    else if (e < 131072) { W = w1; N = 256; base = 65536;  e -= 65536; }
    else if (e < 147456) { W = w2; N = 128; base = 131072; e -= 131072; }
    else return;
    int j = e & 7;
    int lane = (e >> 3) & 63;
    int qt = e >> 9;
    int NT = N >> 4;
    int t = qt % NT;
    int q = qt / NT;
    int u = q * 32 + ((lane >> 4) << 3) + j;
    int w = t * 16 + (lane & 15);
    ws[base + e] = f2bf(W[u * N + w]);
}

// ---------------- main kernel ----------------------------------------------
// D = irrep dim, K = mul (contraction), NT = total 16-wide w-tiles,
// NTW = w-tiles per wave (NT/4), OFF = column offset of this block.
// MFMA 16x16x32_bf16 layouts (HW-verified per guide):
//   A: lane holds A[m=lane&15][k=(lane>>4)*8+j]
//   B: lane holds B[k=(lane>>4)*8+j][n=lane&15]
//   C/D: reg r holds C[row=(lane>>4)*4+r][col=lane&15]
template<int D, int K, int NT, int NTW, int OFF>
__device__ __forceinline__ void run_block(const float* __restrict__ x,
                                          float* __restrict__ out,
                                          const short8* __restrict__ bsw,
                                          float pw,
                                          char* __restrict__ sm) {
    constexpr int COLS   = K * D;            // fp32 elems per row, this block
    constexpr int C4     = COLS / 4;         // float4 chunks per row
    constexpr int RB     = COLS * 2;         // LDS row stride, bytes (bf16)
    constexpr int ROUNDS = (16 * C4) / 256;  // stage rounds for 256 threads

    const int tid  = threadIdx.x;
    const int lane = tid & 63;
    const int wave = tid >> 6;
    const int b0   = blockIdx.x << 4;

    // ---- stage: coalesced global float4 -> bf16x4 -> swizzled LDS ----
#pragma unroll
    for (int rr = 0; rr < ROUNDS; ++rr) {
        int c    = rr * 256 + tid;
        int row  = c / C4;          // compile-time-constant divisor
        int col4 = c - row * C4;
        float4 v = *((const float4*)(x + (size_t)(b0 + row) * NTOTAL + OFF)
                     + col4);
        unsigned long long pk =
              (unsigned long long)f2bf(v.x)
            | ((unsigned long long)f2bf(v.y) << 16)
            | ((unsigned long long)f2bf(v.z) << 32)
            | ((unsigned long long)f2bf(v.w) << 48);
        // XOR swizzle in bits 4-6: RB % 128 == 0 for all blocks, so without
        // it all 16 rows alias the same banks on the b128 fragment reads.
        *(unsigned long long*)(sm + row * RB + ((col4 * 8) ^ ((row & 7) << 4)))
            = pk;
    }
    __syncthreads();

    const int bcol = lane & 15;   // A row (m) / C col (n)
    const int quad = lane >> 4;
    const char* lrow = sm + bcol * RB;
    const int sw = (bcol & 7) << 4;

    f32x4 acc[NTW][D];
#pragma unroll
    for (int tt = 0; tt < NTW; ++tt)
#pragma unroll
        for (int i = 0; i < D; ++i)
            acc[tt][i] = (f32x4){0.f, 0.f, 0.f, 0.f};

#pragma unroll
    for (int q = 0; q < K / 32; ++q) {
        // lane's 8*D consecutive bf16 (cols (q*32+quad*8)*D ..): D b128 reads
        const int cb = (q * 32 + quad * 8) * D * 2;   // multiple of 16
        short8 raw[D];
#pragma unroll
        for (int m = 0; m < D; ++m)
            raw[m] = *(const short8*)(lrow + ((cb + m * 16) ^ sw));

        // repack to fragment order: af[i][j] = elem(col = j*D + i)
        short8 af[D];
#pragma unroll
        for (int i = 0; i < D; ++i)
#pragma unroll
            for (int j = 0; j < 8; ++j) {
                const int e = j * D + i;
                af[i][j] = raw[e >> 3][e & 7];
            }

#pragma unroll
        for (int tt = 0; tt < NTW; ++tt) {
            const int t = wave * NTW + tt;
            short8 bf = bsw[(q * NT + t) * 64 + lane];
#pragma unroll
            for (int i = 0; i < D; ++i)
                acc[tt][i] = __builtin_amdgcn_mfma_f32_16x16x32_bf16(
                    af[i], bf, acc[tt][i], 0, 0, 0);
        }
    }

    // epilogue: y[b0+quad*4+r][OFF + (t*16+bcol)*D + i] = pw * acc
#pragma unroll
    for (int tt = 0; tt < NTW; ++tt) {
        const int wcol = (wave * NTW + tt) * 16 + bcol;
#pragma unroll
        for (int r = 0; r < 4; ++r) {
            float* op = out + (size_t)(b0 + quad * 4 + r) * NTOTAL + OFF
                        + wcol * D;
#pragma unroll
            for (int i = 0; i < D; ++i)
                op[i] = acc[tt][i][r] * pw;
        }
    }
}

__global__ __launch_bounds__(256, 4)
void linear_kernel(const float* __restrict__ x, float* __restrict__ out,
                   const unsigned short* __restrict__ ws) {
    // max LDS need: block1 = 16 rows * 768 bf16 = 24576 B -> up to 6 WG/CU
    __shared__ __attribute__((aligned(16))) char sm[24576];
    const short8* bs0 = (const short8*)(ws);
    const short8* bs1 = (const short8*)(ws + 65536);
    const short8* bs2 = (const short8*)(ws + 131072);
    if (blockIdx.y == 0)
        run_block<1, 256, 16, 4, 0>(x, out, bs0, 0.0625f, sm);
    else if (blockIdx.y == 1)
        run_block<3, 256, 16, 4, 256>(x, out, bs1, 0.0625f, sm);
    else
        run_block<5, 128, 8, 2, 1024>(x, out, bs2, 0.08838834764831845f, sm);
}

extern "C" void kernel_launch(void* const* d_in, const int* in_sizes, int n_in,
                              void* d_out, int out_size, void* d_ws,
                              size_t ws_size, hipStream_t stream) {
    const float* x  = (const float*)d_in[0];
    const float* w0 = (const float*)d_in[1];
    const float* w1 = (const float*)d_in[2];
    const float* w2 = (const float*)d_in[3];
    unsigned short* ws = (unsigned short*)d_ws;  // needs 294912 B

    prep_kernel<<<dim3(576), 256, 0, stream>>>(w0, w1, w2, ws);

    dim3 grid(NBATCH / 16, 3);  // 50000 = 16 * 3125 exactly
    linear_kernel<<<grid, 256, 0, stream>>>(x, (float*)d_out, ws);
}